// Round 5
// baseline (6109.510 us; speedup 1.0000x reference)
//
#include <hip/hip_runtime.h>

#define Bn 512
#define Tn 256
#define Fn 128
#define Hn 512
#define KIE 20   // 640/32 k-iters (encoder: [x|h], K=640)
#define KID 16   // 512/32 k-iters (decoder: h only, K=512)
#define NWG 256
#define RS 648   // A_lds row stride in ushorts (16B-aligned)

typedef __attribute__((ext_vector_type(8))) __bf16 bf16x8;
typedef __attribute__((ext_vector_type(4))) float floatx4;

__device__ __forceinline__ unsigned short f2bf_u16(float f) {
  union { float f; unsigned u; } v; v.f = f;
  unsigned r = v.u + 0x7FFFu + ((v.u >> 16) & 1u);   // RNE
  return (unsigned short)(r >> 16);
}

// fast sigmoid/tanh via v_exp_f32 + v_rcp_f32 (error ~1e-6, << bf16 rounding)
__device__ __forceinline__ float sigm(float x) {
  return __builtin_amdgcn_rcpf(1.f + __expf(-x));
}
__device__ __forceinline__ float ftanh(float x) {
  return 1.f - 2.f * __builtin_amdgcn_rcpf(1.f + __expf(2.f * x));
}

// ---- pack encoder weights [x|h] -> B-fragment order [nt][ki][lane][8] ----
__global__ void pack_enc_k(const float* __restrict__ Wih, const float* __restrict__ Whh,
                           unsigned short* __restrict__ Bpe) {
  int id = blockIdx.x;              // nt*KIE + ki
  int nt = id / KIE, ki = id % KIE;
  int l = threadIdx.x;
  int n = nt * 16 + (l & 15);
  int kb = ki * 32 + (l >> 4) * 8;
  __align__(16) unsigned short o[8];
#pragma unroll
  for (int j = 0; j < 8; ++j) {
    int k = kb + j;
    float v = (k < Fn) ? Wih[n * Fn + k] : Whh[n * Hn + (k - Fn)];
    o[j] = f2bf_u16(v);
  }
  *(uint4*)(Bpe + (size_t)(id * 64 + l) * 8) = *(uint4*)o;
}

// ---- pack decoder combined weights (W_hh + W_ih@Wo) -> fragment order ----
__global__ void pack_dec_k(const float* __restrict__ Wih, const float* __restrict__ Whh,
                           const float* __restrict__ Wo, unsigned short* __restrict__ Bpd) {
  int id = blockIdx.x;              // nt*KID + ki
  int nt = id / KID, ki = id % KID;
  int l = threadIdx.x;
  int n = nt * 16 + (l & 15);
  int kb = ki * 32 + (l >> 4) * 8;
  float acc[8];
#pragma unroll
  for (int j = 0; j < 8; ++j) acc[j] = Whh[n * Hn + kb + j];
  for (int f = 0; f < Fn; ++f) {
    float wf = Wih[n * Fn + f];
    const float* wo = Wo + f * Hn + kb;
#pragma unroll
    for (int j = 0; j < 8; ++j) acc[j] += wf * wo[j];
  }
  __align__(16) unsigned short o[8];
#pragma unroll
  for (int j = 0; j < 8; ++j) o[j] = f2bf_u16(acc[j]);
  *(uint4*)(Bpd + (size_t)(id * 64 + l) * 8) = *(uint4*)o;
}

// ---- pack Wo (for y = h@Wo.T) -> fragment order [ft][ki][lane][8] ----
__global__ void pack_wo_k(const float* __restrict__ Wo, unsigned short* __restrict__ Bpw) {
  int id = blockIdx.x;              // ft*KID + ki
  int ft = id / KID, ki = id % KID;
  int l = threadIdx.x;
  int f = ft * 16 + (l & 15);
  int kb = ki * 32 + (l >> 4) * 8;
  __align__(16) unsigned short o[8];
#pragma unroll
  for (int j = 0; j < 8; ++j) o[j] = f2bf_u16(Wo[f * Hn + kb + j]);
  *(uint4*)(Bpw + (size_t)(id * 64 + l) * 8) = *(uint4*)o;
}

// ---- biases: benc = eb_ih+eb_hh ; bdec = db_ih+db_hh + dW_ih@bo ----
__global__ void bias_k(const float* __restrict__ ebih, const float* __restrict__ ebhh,
                       const float* __restrict__ dbih, const float* __restrict__ dbhh,
                       const float* __restrict__ dWih, const float* __restrict__ bo,
                       float* __restrict__ benc, float* __restrict__ bdec) {
  int n = blockIdx.x * blockDim.x + threadIdx.x;  // 2048
  benc[n] = ebih[n] + ebhh[n];
  float a = dbih[n] + dbhh[n];
  for (int f = 0; f < Fn; ++f) a += dWih[n * Fn + f] * bo[f];
  bdec[n] = a;
}

// ---- pack x: ts[b][s][k] fp32 -> xp[s][b][k] bf16 ----
__global__ void pack_x_k(const float* __restrict__ ts, unsigned short* __restrict__ xp) {
  size_t i = (size_t)blockIdx.x * 256 + threadIdx.x;   // quad index
  int k4 = (int)(i & 31);
  size_t bs = i >> 5;
  int s = (int)(bs & 255);
  size_t b = bs >> 8;
  float4 v = *(const float4*)(ts + (i << 2));
  __align__(8) unsigned short o[4];
  o[0] = f2bf_u16(v.x); o[1] = f2bf_u16(v.y); o[2] = f2bf_u16(v.z); o[3] = f2bf_u16(v.w);
  *(unsigned long long*)(xp + ((size_t)s * Bn + b) * Fn + k4 * 4) = *(unsigned long long*)o;
}

// ---- init: zero BOTH Hg32 buffers (2 MB): h=0, tag=0 ----
__global__ void init_k(unsigned long long* __restrict__ Hg0) {
  size_t i = (size_t)blockIdx.x * 256 + threadIdx.x;   // 1024*256 = 262144 u64
  Hg0[i] = 0ULL;
}

// spin-load 16 tagged words (one producer each), strip tags, write LDS
#define SPIN_H(bb, OFF, bufi, tg) do { \
  const unsigned* src_ = Hg + (size_t)(bufi) * (Bn * Hn) + (size_t)((bb) + sr) * Hn + sc; \
  unsigned v_[16]; \
  int tries_ = 0; \
  for (;;) { \
    _Pragma("unroll") for (int i = 0; i < 16; ++i) \
      v_[i] = __hip_atomic_load(src_ + i, __ATOMIC_RELAXED, __HIP_MEMORY_SCOPE_AGENT); \
    unsigned bad_ = 0; \
    _Pragma("unroll") for (int i = 0; i < 16; ++i) bad_ |= (v_[i] >> 16) ^ (unsigned)(tg); \
    if (!bad_ || ++tries_ > 200000) break; \
    __builtin_amdgcn_s_sleep(0); \
  } \
  uint4 o0_, o1_; \
  o0_.x = (v_[0] & 0xffffu) | (v_[1] << 16);  o0_.y = (v_[2] & 0xffffu) | (v_[3] << 16); \
  o0_.z = (v_[4] & 0xffffu) | (v_[5] << 16);  o0_.w = (v_[6] & 0xffffu) | (v_[7] << 16); \
  o1_.x = (v_[8] & 0xffffu) | (v_[9] << 16);  o1_.y = (v_[10] & 0xffffu) | (v_[11] << 16); \
  o1_.z = (v_[12] & 0xffffu) | (v_[13] << 16); o1_.w = (v_[14] & 0xffffu) | (v_[15] << 16); \
  *(uint4*)&A_lds[sr * RS + (OFF) + sc] = o0_; \
  *(uint4*)&A_lds[sr * RS + (OFF) + sc + 8] = o1_; \
} while (0)

#define PREF_X(s_, bb) (*(const uint2*)(xp + ((size_t)(s_) * Bn + (bb) + sr) * Fn + (tid & 31) * 4))
#define WRITE_X(xv) do { *(uint2*)&A_lds[sr * RS + (tid & 31) * 4] = (xv); } while (0)

#define MFMA_GATES(BR, KN) do { \
  floatx4 acc_ = {0.f, 0.f, 0.f, 0.f}; \
  const unsigned short* Ar_ = &A_lds[l15 * RS + q * 8]; \
  _Pragma("unroll") for (int k = 0; k < (KN); ++k) \
    acc_ = __builtin_amdgcn_mfma_f32_16x16x32_bf16(*(const bf16x8*)(Ar_ + k * 32), (BR)[k], acc_, 0, 0, 0); \
  _Pragma("unroll") for (int r = 0; r < 4; ++r) \
    gates_lds[g_][q * 4 + r][nsub * 16 + l15] = acc_[r]; \
} while (0)

#define MFMA_GATES_Y(BR, doY, bb, sd) do { \
  floatx4 acc_ = {0.f, 0.f, 0.f, 0.f}, accy_ = {0.f, 0.f, 0.f, 0.f}; \
  const unsigned short* Ar_ = &A_lds[l15 * RS + q * 8]; \
  _Pragma("unroll") for (int k = 0; k < KID; ++k) { \
    bf16x8 a_ = *(const bf16x8*)(Ar_ + k * 32); \
    acc_ = __builtin_amdgcn_mfma_f32_16x16x32_bf16(a_, (BR)[k], acc_, 0, 0, 0); \
    if (doY) accy_ = __builtin_amdgcn_mfma_f32_16x16x32_bf16( \
        a_, *(const bf16x8*)&Bw_lds[(k * 64 + l) * 8], accy_, 0, 0, 0); \
  } \
  _Pragma("unroll") for (int r = 0; r < 4; ++r) \
    gates_lds[g_][q * 4 + r][nsub * 16 + l15] = acc_[r]; \
  if (doY) { \
    _Pragma("unroll") for (int r = 0; r < 4; ++r) \
      __builtin_nontemporal_store(accy_[r] + bof, \
        out + ((size_t)((bb) + q * 4 + r) * Tn + (Tn - 1 - (sd))) * Fn + ns * 16 + l15); \
  } \
} while (0)

// epilogue: one h value/thread; tagged 4B store IS the flag (no drain needed)
#define EPI(cvar, BI, BF, BG, BO, bb, nxtbuf, ntg) do { \
  float gi_ = gates_lds[0][sr][ec] + (BI); \
  float gf_ = gates_lds[1][sr][ec] + (BF); \
  float gg_ = gates_lds[2][sr][ec] + (BG); \
  float go_ = gates_lds[3][sr][ec] + (BO); \
  cvar = sigm(gf_) * cvar + sigm(gi_) * ftanh(gg_); \
  float h_ = sigm(go_) * ftanh(cvar); \
  unsigned w_ = (unsigned)f2bf_u16(h_) | ((unsigned)(ntg) << 16); \
  __hip_atomic_store(Hg + (size_t)(nxtbuf) * (Bn * Hn) + (size_t)((bb) + sr) * Hn + j0 + ec, \
      w_, __ATOMIC_RELAXED, __HIP_MEMORY_SCOPE_AGENT); \
} while (0)

// ---- persistent LSTM enc-dec: 256 wgs x 512 thr, tagged-dataflow sync ----
__global__ __launch_bounds__(512, 2) void lstm_persist(
    const unsigned short* __restrict__ xp,
    const unsigned short* __restrict__ Bpe,
    const unsigned short* __restrict__ Bpd,
    const unsigned short* __restrict__ Bpw,
    const float* __restrict__ benc,
    const float* __restrict__ bdec,
    const float* __restrict__ bo,
    unsigned* __restrict__ Hg,         // [2][512][512] u32 (bf16 h | tag<<16)
    float* __restrict__ out)           // [512][256][128] fp32
{
  const int wg = blockIdx.x;
  const int mg = wg >> 4, ns = wg & 15;
  const int b0 = mg * 32, j0 = ns * 32;
  const int tid = threadIdx.x;
  const int w = tid >> 6, l = tid & 63;
  const int l15 = l & 15, q = l >> 4;
  const int g_ = w >> 1, nsub = w & 1;       // wave = (gate, 16-col subtile)
  const int nt = g_ * 32 + ns * 2 + nsub;
  const int sr = tid >> 5;                   // staging/epilogue row 0..15
  const int sc = (tid & 31) * 16;            // staging col (words)
  const int ec = tid & 31;                   // epilogue col 0..31

  __shared__ __align__(16) unsigned short A_lds[16 * RS];        // 20.7 KB
  __shared__ __align__(16) float gates_lds[4][16][34];           //  8.7 KB
  __shared__ __align__(16) unsigned short Bw_lds[KID * 64 * 8];  // 16.4 KB

  // ---- preload B tiles (enc + dec) into registers/AGPRs ----
  bf16x8 Bq[KIE], Bd[KID];
  {
    const bf16x8* p = (const bf16x8*)Bpe + (size_t)nt * (KIE * 64) + l;
#pragma unroll
    for (int k = 0; k < KIE; ++k) Bq[k] = p[k * 64];
  }
  {
    const bf16x8* p = (const bf16x8*)Bpd + (size_t)nt * (KID * 64) + l;
#pragma unroll
    for (int k = 0; k < KID; ++k) Bd[k] = p[k * 64];
  }
  // per-thread gate biases (row sr, col ec of this wg's 32-col slice)
  const float bie = benc[0 * Hn + j0 + ec], bfe = benc[1 * Hn + j0 + ec];
  const float bge = benc[2 * Hn + j0 + ec], boe = benc[3 * Hn + j0 + ec];
  const float bid = bdec[0 * Hn + j0 + ec], bfd = bdec[1 * Hn + j0 + ec];
  const float bgd = bdec[2 * Hn + j0 + ec], bod = bdec[3 * Hn + j0 + ec];

  if (ns < 8) { // constant Wo slice -> LDS, once
    const uint4* src = (const uint4*)(Bpw + (size_t)ns * (KID * 64 * 8));
    uint4* dst = (uint4*)Bw_lds;
    dst[tid * 2] = src[tid * 2];
    dst[tid * 2 + 1] = src[tid * 2 + 1];
  }
  const bool yA = (ns < 8) && (w == 0);
  const bool yB = (ns < 8) && (w == 4);
  float bof = 0.f;
  if (yA || yB) bof = bo[ns * 16 + l15];

  const int bbA = b0, bbB = b0 + 16;
  float cA = 0.f, cB = 0.f;

  // prefetch x_0 for both streams
  uint2 xpA = PREF_X(0, bbA);
  uint2 xpB = PREF_X(0, bbB);

  // ================= encoder =================
  for (int s = 0; s < Tn; ++s) {
    const int cur = s & 1, nxt = cur ^ 1;
    SPIN_H(bbA, Fn, cur, s);
    WRITE_X(xpA);
    __syncthreads();                 // (1) A staged
    MFMA_GATES(Bq, KIE);
    __syncthreads();                 // (2) gates_A ready, A_lds free
    EPI(cA, bie, bfe, bge, boe, bbA, nxt, s + 1);   // fire-and-forget tagged store
    SPIN_H(bbB, Fn, cur, s);
    WRITE_X(xpB);
    { int sn = (s + 1 < Tn) ? s + 1 : Tn - 1; xpA = PREF_X(sn, bbA); }
    __syncthreads();                 // (3) B staged; gates_A reads done
    MFMA_GATES(Bq, KIE);
    __syncthreads();                 // (4) gates_B ready, A_lds free
    EPI(cB, bie, bfe, bge, boe, bbB, nxt, s + 1);
    { int sn = (s + 1 < Tn) ? s + 1 : Tn - 1; xpB = PREF_X(sn, bbB); }
  }

  // ================= decoder =================
  cA = 0.f; cB = 0.f;                // reference restarts c at zero
  for (int sd = 0; sd < Tn; ++sd) {
    const int phg = Tn + sd;
    const int cur = phg & 1, nxt = cur ^ 1;
    SPIN_H(bbA, 0, cur, phg);
    __syncthreads();                 // (1)
    MFMA_GATES_Y(Bd, yA, bbA, sd);
    __syncthreads();                 // (2)
    EPI(cA, bid, bfd, bgd, bod, bbA, nxt, phg + 1);
    SPIN_H(bbB, 0, cur, phg);
    __syncthreads();                 // (3)
    MFMA_GATES_Y(Bd, yB, bbB, sd);
    __syncthreads();                 // (4)
    EPI(cB, bid, bfd, bgd, bod, bbB, nxt, phg + 1);
  }
}

extern "C" void kernel_launch(void* const* d_in, const int* in_sizes, int n_in,
                              void* d_out, int out_size, void* d_ws, size_t ws_size,
                              hipStream_t stream) {
  const float* ts   = (const float*)d_in[0];
  const float* eWih = (const float*)d_in[1];
  const float* eWhh = (const float*)d_in[2];
  const float* ebih = (const float*)d_in[3];
  const float* ebhh = (const float*)d_in[4];
  const float* dWih = (const float*)d_in[5];
  const float* dWhh = (const float*)d_in[6];
  const float* dbih = (const float*)d_in[7];
  const float* dbhh = (const float*)d_in[8];
  const float* Wo   = (const float*)d_in[9];
  const float* bo   = (const float*)d_in[10];
  float* outp = (float*)d_out;

  char* ws = (char*)d_ws;
  unsigned short* Bpe  = (unsigned short*)(ws);                 // 2,621,440 B
  unsigned short* Bpd  = (unsigned short*)(ws + 2621440);       // 2,097,152 B
  unsigned short* Bpw  = (unsigned short*)(ws + 4718592);       //   131,072 B
  float*          benc = (float*)(ws + 4849664);                //     8,192 B
  float*          bdec = (float*)(ws + 4857856);                //     8,192 B
  unsigned*       Hg   = (unsigned*)(ws + 4866048);             // 2,097,152 B
  unsigned short* xp   = (unsigned short*)(ws + 6963200);       // 16,777,216 B

  pack_enc_k<<<128 * KIE, 64, 0, stream>>>(eWih, eWhh, Bpe);
  pack_dec_k<<<128 * KID, 64, 0, stream>>>(dWih, dWhh, Wo, Bpd);
  pack_wo_k<<<8 * KID, 64, 0, stream>>>(Wo, Bpw);
  bias_k<<<8, 256, 0, stream>>>(ebih, ebhh, dbih, dbhh, dWih, bo, benc, bdec);
  pack_x_k<<<16384, 256, 0, stream>>>(ts, xp);
  init_k<<<1024, 256, 0, stream>>>((unsigned long long*)Hg);

  lstm_persist<<<NWG, 512, 0, stream>>>(xp, Bpe, Bpd, Bpw, benc, bdec, bo, Hg, outp);
}

// Round 6
// 2878.422 us; speedup vs baseline: 2.1225x; 2.1225x over previous
//
#include <hip/hip_runtime.h>

#define Bn 512
#define Tn 256
#define Fn 128
#define Hn 512
#define KIE 20   // 640/32 k-iters (encoder: [x|h], K=640)
#define KID 16   // 512/32 k-iters (decoder: h only, K=512)
#define NWG 256
#define RS 648   // A_lds row stride in ushorts (16B-aligned)

typedef __attribute__((ext_vector_type(8))) __bf16 bf16x8;
typedef __attribute__((ext_vector_type(4))) float floatx4;

__device__ __forceinline__ unsigned short f2bf_u16(float f) {
  union { float f; unsigned u; } v; v.f = f;
  unsigned r = v.u + 0x7FFFu + ((v.u >> 16) & 1u);   // RNE
  return (unsigned short)(r >> 16);
}

// fast sigmoid/tanh via v_exp_f32 + v_rcp_f32 (error ~1e-6, << bf16 rounding)
__device__ __forceinline__ float sigm(float x) {
  return __builtin_amdgcn_rcpf(1.f + __expf(-x));
}
__device__ __forceinline__ float ftanh(float x) {
  return 1.f - 2.f * __builtin_amdgcn_rcpf(1.f + __expf(2.f * x));
}

// ---- pack encoder weights [x|h] -> B-fragment order [nt][ki][lane][8] ----
__global__ void pack_enc_k(const float* __restrict__ Wih, const float* __restrict__ Whh,
                           unsigned short* __restrict__ Bpe) {
  int id = blockIdx.x;              // nt*KIE + ki
  int nt = id / KIE, ki = id % KIE;
  int l = threadIdx.x;
  int n = nt * 16 + (l & 15);
  int kb = ki * 32 + (l >> 4) * 8;
  __align__(16) unsigned short o[8];
#pragma unroll
  for (int j = 0; j < 8; ++j) {
    int k = kb + j;
    float v = (k < Fn) ? Wih[n * Fn + k] : Whh[n * Hn + (k - Fn)];
    o[j] = f2bf_u16(v);
  }
  *(uint4*)(Bpe + (size_t)(id * 64 + l) * 8) = *(uint4*)o;
}

// ---- pack decoder combined weights (W_hh + W_ih@Wo) -> fragment order ----
__global__ void pack_dec_k(const float* __restrict__ Wih, const float* __restrict__ Whh,
                           const float* __restrict__ Wo, unsigned short* __restrict__ Bpd) {
  int id = blockIdx.x;              // nt*KID + ki
  int nt = id / KID, ki = id % KID;
  int l = threadIdx.x;
  int n = nt * 16 + (l & 15);
  int kb = ki * 32 + (l >> 4) * 8;
  float acc[8];
#pragma unroll
  for (int j = 0; j < 8; ++j) acc[j] = Whh[n * Hn + kb + j];
  for (int f = 0; f < Fn; ++f) {
    float wf = Wih[n * Fn + f];
    const float* wo = Wo + f * Hn + kb;
#pragma unroll
    for (int j = 0; j < 8; ++j) acc[j] += wf * wo[j];
  }
  __align__(16) unsigned short o[8];
#pragma unroll
  for (int j = 0; j < 8; ++j) o[j] = f2bf_u16(acc[j]);
  *(uint4*)(Bpd + (size_t)(id * 64 + l) * 8) = *(uint4*)o;
}

// ---- pack Wo (for y = h@Wo.T) -> fragment order [ft][ki][lane][8] ----
__global__ void pack_wo_k(const float* __restrict__ Wo, unsigned short* __restrict__ Bpw) {
  int id = blockIdx.x;              // ft*KID + ki
  int ft = id / KID, ki = id % KID;
  int l = threadIdx.x;
  int f = ft * 16 + (l & 15);
  int kb = ki * 32 + (l >> 4) * 8;
  __align__(16) unsigned short o[8];
#pragma unroll
  for (int j = 0; j < 8; ++j) o[j] = f2bf_u16(Wo[f * Hn + kb + j]);
  *(uint4*)(Bpw + (size_t)(id * 64 + l) * 8) = *(uint4*)o;
}

// ---- biases: benc = eb_ih+eb_hh ; bdec = db_ih+db_hh + dW_ih@bo ----
__global__ void bias_k(const float* __restrict__ ebih, const float* __restrict__ ebhh,
                       const float* __restrict__ dbih, const float* __restrict__ dbhh,
                       const float* __restrict__ dWih, const float* __restrict__ bo,
                       float* __restrict__ benc, float* __restrict__ bdec) {
  int n = blockIdx.x * blockDim.x + threadIdx.x;  // 2048
  benc[n] = ebih[n] + ebhh[n];
  float a = dbih[n] + dbhh[n];
  for (int f = 0; f < Fn; ++f) a += dWih[n * Fn + f] * bo[f];
  bdec[n] = a;
}

// ---- pack x: ts[b][s][k] fp32 -> xp[s][b][k] bf16 ----
__global__ void pack_x_k(const float* __restrict__ ts, unsigned short* __restrict__ xp) {
  size_t i = (size_t)blockIdx.x * 256 + threadIdx.x;   // quad index
  int k4 = (int)(i & 31);
  size_t bs = i >> 5;
  int s = (int)(bs & 255);
  size_t b = bs >> 8;
  float4 v = *(const float4*)(ts + (i << 2));
  __align__(8) unsigned short o[4];
  o[0] = f2bf_u16(v.x); o[1] = f2bf_u16(v.y); o[2] = f2bf_u16(v.z); o[3] = f2bf_u16(v.w);
  *(unsigned long long*)(xp + ((size_t)s * Bn + b) * Fn + k4 * 4) = *(unsigned long long*)o;
}

// ---- init: zero Hg buffer 0 (512 KB) + both flag arrays ----
__global__ void init_k(unsigned long long* __restrict__ Hg0,
                       unsigned* __restrict__ flgA, unsigned* __restrict__ flgB) {
  int i = blockIdx.x * 256 + threadIdx.x;   // 65536
  Hg0[i] = 0ULL;
  if (i < 8192) { flgA[i] = 0u; flgB[i] = 0u; }
}

#define POLL(F, p) do { \
  if (l < 16) { \
    const unsigned* fp_ = (F) + (size_t)(mg * 16 + l) * 32; \
    while (__hip_atomic_load(fp_, __ATOMIC_RELAXED, __HIP_MEMORY_SCOPE_AGENT) < (unsigned)(p)) \
      __builtin_amdgcn_s_sleep(1); \
  } \
  __asm__ __volatile__("" ::: "memory"); \
} while (0)

// issue h loads (32B/thread) into regs; write later
#define ISSUE_H(dst, bb, bufi) do { \
  const unsigned long long* s_ = (const unsigned long long*) \
      (Hg + (size_t)(bufi) * (Bn * Hn) + (size_t)((bb) + sr) * Hn + scb); \
  dst[0] = __hip_atomic_load(s_ + 0, __ATOMIC_RELAXED, __HIP_MEMORY_SCOPE_AGENT); \
  dst[1] = __hip_atomic_load(s_ + 1, __ATOMIC_RELAXED, __HIP_MEMORY_SCOPE_AGENT); \
  dst[2] = __hip_atomic_load(s_ + 2, __ATOMIC_RELAXED, __HIP_MEMORY_SCOPE_AGENT); \
  dst[3] = __hip_atomic_load(s_ + 3, __ATOMIC_RELAXED, __HIP_MEMORY_SCOPE_AGENT); \
} while (0)

#define WRITE_H(Albs, OFF, src) do { \
  uint4 t0_, t1_; \
  t0_.x = (unsigned)src[0]; t0_.y = (unsigned)(src[0] >> 32); \
  t0_.z = (unsigned)src[1]; t0_.w = (unsigned)(src[1] >> 32); \
  t1_.x = (unsigned)src[2]; t1_.y = (unsigned)(src[2] >> 32); \
  t1_.z = (unsigned)src[3]; t1_.w = (unsigned)(src[3] >> 32); \
  *(uint4*)&(Albs)[sr * RS + (OFF) + scb] = t0_; \
  *(uint4*)&(Albs)[sr * RS + (OFF) + scb + 8] = t1_; \
} while (0)

#define ISSUE_X(dst, s_, bb) do { \
  dst = *(const uint2*)(xp + ((size_t)(s_) * Bn + (bb) + sr) * Fn + (tid & 31) * 4); \
} while (0)

#define WRITE_X(Albs, src) do { \
  *(uint2*)&(Albs)[sr * RS + (tid & 31) * 4] = (src); \
} while (0)

#define MFMA_GATES(Albs, BR, KN) do { \
  floatx4 acc_ = {0.f, 0.f, 0.f, 0.f}; \
  const unsigned short* Ar_ = &(Albs)[l15 * RS + q * 8]; \
  _Pragma("unroll") for (int k = 0; k < (KN); ++k) \
    acc_ = __builtin_amdgcn_mfma_f32_16x16x32_bf16(*(const bf16x8*)(Ar_ + k * 32), (BR)[k], acc_, 0, 0, 0); \
  _Pragma("unroll") for (int r = 0; r < 4; ++r) \
    gates_lds[g_][q * 4 + r][nsub * 16 + l15] = acc_[r]; \
} while (0)

#define MFMA_GATES_Y(Albs, BR, doY, bb, sd) do { \
  floatx4 acc_ = {0.f, 0.f, 0.f, 0.f}, accy_ = {0.f, 0.f, 0.f, 0.f}; \
  const unsigned short* Ar_ = &(Albs)[l15 * RS + q * 8]; \
  _Pragma("unroll") for (int k = 0; k < KID; ++k) { \
    bf16x8 a_ = *(const bf16x8*)(Ar_ + k * 32); \
    acc_ = __builtin_amdgcn_mfma_f32_16x16x32_bf16(a_, (BR)[k], acc_, 0, 0, 0); \
    if (doY) accy_ = __builtin_amdgcn_mfma_f32_16x16x32_bf16( \
        a_, *(const bf16x8*)&Bw_lds[(k * 64 + l) * 8], accy_, 0, 0, 0); \
  } \
  _Pragma("unroll") for (int r = 0; r < 4; ++r) \
    gates_lds[g_][q * 4 + r][nsub * 16 + l15] = acc_[r]; \
  if (doY) { \
    _Pragma("unroll") for (int r = 0; r < 4; ++r) \
      __builtin_nontemporal_store(accy_[r] + bof, \
        out + ((size_t)((bb) + q * 4 + r) * Tn + (Tn - 1 - (sd))) * Fn + ns * 16 + l15); \
  } \
} while (0)

#define EPI(cvar, BI, BF, BG, BO, bb, nxtbuf) do { \
  float gi_ = gates_lds[0][sr][ec] + (BI); \
  float gf_ = gates_lds[1][sr][ec] + (BF); \
  float gg_ = gates_lds[2][sr][ec] + (BG); \
  float go_ = gates_lds[3][sr][ec] + (BO); \
  cvar = sigm(gf_) * cvar + sigm(gi_) * ftanh(gg_); \
  float h_ = sigm(go_) * ftanh(cvar); \
  __hip_atomic_store(Hg + (size_t)(nxtbuf) * (Bn * Hn) + (size_t)((bb) + sr) * Hn + j0 + ec, \
      (unsigned short)f2bf_u16(h_), __ATOMIC_RELAXED, __HIP_MEMORY_SCOPE_AGENT); \
} while (0)

// wave-level publication: waitcnt own stores, LDS fan-in, 8th wave fires flag
#define PUBLISH(F, cnt, p1) do { \
  __asm__ __volatile__("s_waitcnt vmcnt(0)" ::: "memory"); \
  if (l == 0) { \
    unsigned o_ = atomicAdd(&(cnt), 1u); \
    if ((o_ & 7u) == 7u) \
      __hip_atomic_store((F) + (size_t)wg * 32, (unsigned)(p1), \
                         __ATOMIC_RELAXED, __HIP_MEMORY_SCOPE_AGENT); \
  } \
} while (0)

// ---- persistent LSTM enc-dec: 256 wgs x 512 thr, pipelined 2-stream ----
__global__ __launch_bounds__(512, 2) void lstm_persist(
    const unsigned short* __restrict__ xp,
    const unsigned short* __restrict__ Bpe,
    const unsigned short* __restrict__ Bpd,
    const unsigned short* __restrict__ Bpw,
    const float* __restrict__ benc,
    const float* __restrict__ bdec,
    const float* __restrict__ bo,
    unsigned short* __restrict__ Hg,   // [2][512][512] bf16 (sc1 access only)
    unsigned* __restrict__ flgA,
    unsigned* __restrict__ flgB,
    float* __restrict__ out)           // [512][256][128] fp32
{
  const int wg = blockIdx.x;
  const int mg = wg >> 4, ns = wg & 15;
  const int b0 = mg * 32, j0 = ns * 32;
  const int tid = threadIdx.x;
  const int w = tid >> 6, l = tid & 63;
  const int l15 = l & 15, q = l >> 4;
  const int g_ = w >> 1, nsub = w & 1;       // wave = (gate, 16-col subtile)
  const int nt = g_ * 32 + ns * 2 + nsub;
  const int sr = tid >> 5;                   // staging/epilogue row 0..15
  const int scb = (tid & 31) * 16;           // staging col base (u16 units, 32B/thread)
  const int ec = tid & 31;                   // epilogue col 0..31

  __shared__ __align__(16) unsigned short A_ldsA[16 * RS];       // 20.7 KB
  __shared__ __align__(16) unsigned short A_ldsB[16 * RS];       // 20.7 KB
  __shared__ __align__(16) float gates_lds[4][16][34];           //  8.7 KB
  __shared__ __align__(16) unsigned short Bw_lds[KID * 64 * 8];  // 16.4 KB
  __shared__ unsigned cntA, cntB;

  if (tid == 0) { cntA = 0u; cntB = 0u; }

  // ---- preload B tiles (enc + dec) ----
  bf16x8 Bq[KIE], Bd[KID];
  {
    const bf16x8* p = (const bf16x8*)Bpe + (size_t)nt * (KIE * 64) + l;
#pragma unroll
    for (int k = 0; k < KIE; ++k) Bq[k] = p[k * 64];
  }
  {
    const bf16x8* p = (const bf16x8*)Bpd + (size_t)nt * (KID * 64) + l;
#pragma unroll
    for (int k = 0; k < KID; ++k) Bd[k] = p[k * 64];
  }
  // per-thread gate biases
  const float bie = benc[0 * Hn + j0 + ec], bfe = benc[1 * Hn + j0 + ec];
  const float bge = benc[2 * Hn + j0 + ec], boe = benc[3 * Hn + j0 + ec];
  const float bid = bdec[0 * Hn + j0 + ec], bfd = bdec[1 * Hn + j0 + ec];
  const float bgd = bdec[2 * Hn + j0 + ec], bod = bdec[3 * Hn + j0 + ec];

  if (ns < 8) { // constant Wo slice -> LDS, once
    const uint4* src = (const uint4*)(Bpw + (size_t)ns * (KID * 64 * 8));
    uint4* dst = (uint4*)Bw_lds;
    dst[tid * 2] = src[tid * 2];
    dst[tid * 2 + 1] = src[tid * 2 + 1];
  }
  const bool yA = (ns < 8) && (w == 0);
  const bool yB = (ns < 8) && (w == 4);
  float bof = 0.f;
  if (yA || yB) bof = bo[ns * 16 + l15];

  const int bbA = b0, bbB = b0 + 16;
  float cA = 0.f, cB = 0.f;

  unsigned long long hA_[4], hB_[4];
  uint2 xA_, xB_;

  // pre-loop: phase-0 stream-A data (flags start at 0 => POLL passes)
  ISSUE_H(hA_, bbA, 0);
  ISSUE_X(xA_, 0, bbA);
  __syncthreads();   // cnt init + Bw_lds visible

  for (int ph = 0; ph < 2 * Tn; ++ph) {
    const bool enc = ph < Tn, encN = (ph + 1) < Tn;
    const int cur = ph & 1, nxt = cur ^ 1;
    const int off = enc ? Fn : 0;
    if (ph == Tn) { cA = 0.f; cB = 0.f; }   // decoder restarts c at zero

    // 1. commit stream-A staged regs to LDS
    WRITE_H(A_ldsA, off, hA_);
    if (enc) WRITE_X(A_ldsA, xA_);
    __syncthreads();                         // sync1: A_ldsA ready
    // 2. poll + issue stream-B loads (fly under MFMA A)
    POLL(flgB, ph);
    ISSUE_H(hB_, bbB, cur);
    if (enc) ISSUE_X(xB_, ph, bbB);
    // 3. MFMA stream A
    if (enc) MFMA_GATES(A_ldsA, Bq, KIE);
    else     MFMA_GATES_Y(A_ldsA, Bd, yA, bbA, ph - Tn);
    __syncthreads();                         // sync2: gates A ready
    // 4. epilogue A + immediate publication
    if (enc) EPI(cA, bie, bfe, bge, boe, bbA, nxt);
    else     EPI(cA, bid, bfd, bgd, bod, bbA, nxt);
    PUBLISH(flgA, cntA, ph + 1);
    // 5. commit stream-B staged regs to LDS
    WRITE_H(A_ldsB, off, hB_);
    if (enc) WRITE_X(A_ldsB, xB_);
    __syncthreads();                         // sync3: A_ldsB ready; gates free
    // 6. poll + issue next-phase stream-A loads (fly under MFMA B)
    if (ph + 1 < 2 * Tn) {
      POLL(flgA, ph + 1);
      ISSUE_H(hA_, bbA, nxt);
      if (encN) ISSUE_X(xA_, ph + 1, bbA);
    }
    // 7. MFMA stream B
    if (enc) MFMA_GATES(A_ldsB, Bq, KIE);
    else     MFMA_GATES_Y(A_ldsB, Bd, yB, bbB, ph - Tn);
    __syncthreads();                         // sync4: gates B ready
    // 8. epilogue B + immediate publication
    if (enc) EPI(cB, bie, bfe, bge, boe, bbB, nxt);
    else     EPI(cB, bid, bfd, bgd, bod, bbB, nxt);
    PUBLISH(flgB, cntB, ph + 1);
  }
}

extern "C" void kernel_launch(void* const* d_in, const int* in_sizes, int n_in,
                              void* d_out, int out_size, void* d_ws, size_t ws_size,
                              hipStream_t stream) {
  const float* ts   = (const float*)d_in[0];
  const float* eWih = (const float*)d_in[1];
  const float* eWhh = (const float*)d_in[2];
  const float* ebih = (const float*)d_in[3];
  const float* ebhh = (const float*)d_in[4];
  const float* dWih = (const float*)d_in[5];
  const float* dWhh = (const float*)d_in[6];
  const float* dbih = (const float*)d_in[7];
  const float* dbhh = (const float*)d_in[8];
  const float* Wo   = (const float*)d_in[9];
  const float* bo   = (const float*)d_in[10];
  float* outp = (float*)d_out;

  char* ws = (char*)d_ws;
  unsigned short* Bpe  = (unsigned short*)(ws);                 // 2,621,440 B
  unsigned short* Bpd  = (unsigned short*)(ws + 2621440);       // 2,097,152 B
  unsigned short* Bpw  = (unsigned short*)(ws + 4718592);       //   131,072 B
  float*          benc = (float*)(ws + 4849664);                //     8,192 B
  float*          bdec = (float*)(ws + 4857856);                //     8,192 B
  unsigned short* Hg   = (unsigned short*)(ws + 4866048);       // 1,048,576 B
  unsigned*       flgA = (unsigned*)(ws + 5914624);             //    32,768 B
  unsigned*       flgB = (unsigned*)(ws + 5947392);             //    32,768 B
  unsigned short* xp   = (unsigned short*)(ws + 5980160);       // 16,777,216 B

  pack_enc_k<<<128 * KIE, 64, 0, stream>>>(eWih, eWhh, Bpe);
  pack_dec_k<<<128 * KID, 64, 0, stream>>>(dWih, dWhh, Wo, Bpd);
  pack_wo_k<<<8 * KID, 64, 0, stream>>>(Wo, Bpw);
  bias_k<<<8, 256, 0, stream>>>(ebih, ebhh, dbih, dbhh, dWih, bo, benc, bdec);
  pack_x_k<<<16384, 256, 0, stream>>>(ts, xp);
  init_k<<<256, 256, 0, stream>>>((unsigned long long*)Hg, flgA, flgB);

  lstm_persist<<<NWG, 512, 0, stream>>>(xp, Bpe, Bpd, Bpw, benc, bdec, bo, Hg, flgA, flgB, outp);
}